// Round 3
// baseline (496.425 us; speedup 1.0000x reference)
//
#include <hip/hip_runtime.h>

#define NNODES   50000
#define NHEADS   8
#define NCHAN    16
#define ATT_NORM 4.0f
#define EPS_V    1e-12f

typedef float v4f __attribute__((ext_vector_type(4)));

// Pass 1: per-(edge,head) L2 norm of x_j, segment-max into node_max.
// Read-check-skip before atomicMax: node_max is monotone non-decreasing
// from 0, so a stale read is always <= current; skipping when stale >= nj
// is safe, and a redundant atomic is harmless. Converts ~90% of atomics
// into plain L2 loads.
__global__ void lips_pass1(const float* __restrict__ x_j,
                           const int* __restrict__ index,
                           unsigned int* __restrict__ node_max,
                           int EH) {
    int t = blockIdx.x * blockDim.x + threadIdx.x;
    if (t >= EH) return;
    const int e = t >> 3;   // / NHEADS
    const int h = t & 7;    // % NHEADS

    const v4f* p = (const v4f*)(x_j + (size_t)t * NCHAN);
    v4f a = __builtin_nontemporal_load(p + 0);
    v4f b = __builtin_nontemporal_load(p + 1);
    v4f c = __builtin_nontemporal_load(p + 2);
    v4f d = __builtin_nontemporal_load(p + 3);
    float s = a.x*a.x + a.y*a.y + a.z*a.z + a.w*a.w
            + b.x*b.x + b.y*b.y + b.z*b.z + b.w*b.w
            + c.x*c.x + c.y*c.y + c.z*c.z + c.w*c.w
            + d.x*d.x + d.y*d.y + d.z*d.z + d.w*d.w;
    unsigned int nj = __float_as_uint(sqrtf(s));

    const int node = index[e];
    unsigned int* slot = node_max + (size_t)node * NHEADS + h;
    if (__hip_atomic_load(slot, __ATOMIC_RELAXED, __HIP_MEMORY_SCOPE_AGENT) < nj) {
        atomicMax(slot, nj);
    }
}

// Pass 2: recompute ni from x_i, gather node max, divide.
__global__ void lips_pass2(const float* __restrict__ e_ij,
                           const float* __restrict__ x_i,
                           const int* __restrict__ index,
                           const unsigned int* __restrict__ node_max,
                           float* __restrict__ out,
                           int EH) {
    int t = blockIdx.x * blockDim.x + threadIdx.x;
    if (t >= EH) return;
    const int e = t >> 3;
    const int h = t & 7;

    const v4f* p = (const v4f*)(x_i + (size_t)t * NCHAN);
    v4f a = __builtin_nontemporal_load(p + 0);
    v4f b = __builtin_nontemporal_load(p + 1);
    v4f c = __builtin_nontemporal_load(p + 2);
    v4f d = __builtin_nontemporal_load(p + 3);
    float s = a.x*a.x + a.y*a.y + a.z*a.z + a.w*a.w
            + b.x*b.x + b.y*b.y + b.z*b.z + b.w*b.w
            + c.x*c.x + c.y*c.y + c.z*c.z + c.w*c.w
            + d.x*d.x + d.y*d.y + d.z*d.z + d.w*d.w;
    float ni = sqrtf(s);

    const int node = index[e];
    float mnj = __uint_as_float(node_max[(size_t)node * NHEADS + h]);

    float denom = ATT_NORM * (ni + mnj);
    denom = fmaxf(denom, EPS_V);

    float ev = __builtin_nontemporal_load(e_ij + t);
    ev = fminf(fmaxf(ev, -10000.0f), 10000.0f);
    __builtin_nontemporal_store(ev / denom, out + t);
}

extern "C" void kernel_launch(void* const* d_in, const int* in_sizes, int n_in,
                              void* d_out, int out_size, void* d_ws, size_t ws_size,
                              hipStream_t stream) {
    const float* e_ij  = (const float*)d_in[0];
    const float* x_i   = (const float*)d_in[1];
    const float* x_j   = (const float*)d_in[2];
    const int*   index = (const int*)d_in[3];

    float* out = (float*)d_out;
    unsigned int* node_max = (unsigned int*)d_ws;   // [NNODES][NHEADS]

    const int EH = out_size;                        // E * NHEADS = 12.8M
    const int threads = 256;
    const int blocks = (EH + threads - 1) / threads;

    // Zero the segment-max scratch every call (harness does not re-poison).
    (void)hipMemsetAsync(node_max, 0, (size_t)NNODES * NHEADS * sizeof(unsigned int), stream);

    lips_pass1<<<blocks, threads, 0, stream>>>(x_j, index, node_max, EH);
    lips_pass2<<<blocks, threads, 0, stream>>>(e_ij, x_i, index, node_max, out, EH);
}

// Round 4
// 355.079 us; speedup vs baseline: 1.3981x; 1.3981x over previous
//
#include <hip/hip_runtime.h>

#define NNODES   50000
#define NHEADS   8
#define NCHAN    16
#define ATT_NORM 4.0f
#define EPS_V    1e-12f

typedef float    v4f __attribute__((ext_vector_type(4)));
typedef float    v2f __attribute__((ext_vector_type(2)));
typedef unsigned v2u __attribute__((ext_vector_type(2)));

// Pass 1: per-(edge,head) L2 norm of x_j, segment-max into node_max via
// unsigned atomicMax (norms >= 0: IEEE754 order == uint order). Plain
// unconditional atomic (R3 showed agent-scope pre-check reads bypass L2
// and cost more than they save). Grid-stride, 2048 blocks.
__global__ void lips_pass1(const float* __restrict__ x_j,
                           const int* __restrict__ index,
                           unsigned int* __restrict__ node_max,
                           int EH) {
    const int stride = gridDim.x * blockDim.x;
    for (int t = blockIdx.x * blockDim.x + threadIdx.x; t < EH; t += stride) {
        const int e = t >> 3;   // / NHEADS
        const int h = t & 7;    // % NHEADS

        const v4f* p = (const v4f*)(x_j + (size_t)t * NCHAN);
        v4f a = p[0], b = p[1], c = p[2], d = p[3];
        float s = a.x*a.x + a.y*a.y + a.z*a.z + a.w*a.w
                + b.x*b.x + b.y*b.y + b.z*b.z + b.w*b.w
                + c.x*c.x + c.y*c.y + c.z*c.z + c.w*c.w
                + d.x*d.x + d.y*d.y + d.z*d.z + d.w*d.w;
        float nj = sqrtf(s);

        const int node = index[e];
        atomicMax(node_max + (size_t)node * NHEADS + h, __float_as_uint(nj));
    }
}

// Pass 2: two heads per thread. Recompute ni from x_i (128 B/thread
// contiguous), gather both heads' node max as one 8-B load (4 threads of
// the same edge coalesce into one 32-B chunk), vector e_ij load / out store.
__global__ void lips_pass2(const float* __restrict__ e_ij,
                           const float* __restrict__ x_i,
                           const int* __restrict__ index,
                           const unsigned int* __restrict__ node_max,
                           float* __restrict__ out,
                           int EH2) {   // = E * 4 (head-pairs)
    const int stride = gridDim.x * blockDim.x;
    for (int t = blockIdx.x * blockDim.x + threadIdx.x; t < EH2; t += stride) {
        const int e  = t >> 2;   // edge
        const int hp = t & 3;    // head pair (heads 2*hp, 2*hp+1)

        const v4f* p = (const v4f*)(x_i + (size_t)e * (NHEADS * NCHAN) + hp * 2 * NCHAN);
        v4f a0 = p[0], a1 = p[1], a2 = p[2], a3 = p[3];   // head 2*hp
        v4f b0 = p[4], b1 = p[5], b2 = p[6], b3 = p[7];   // head 2*hp+1

        const int node = index[e];
        v2u m  = *(const v2u*)(node_max + (size_t)node * NHEADS + hp * 2);
        v2f ev = *(const v2f*)(e_ij + (size_t)e * NHEADS + hp * 2);

        float s0 = a0.x*a0.x + a0.y*a0.y + a0.z*a0.z + a0.w*a0.w
                 + a1.x*a1.x + a1.y*a1.y + a1.z*a1.z + a1.w*a1.w
                 + a2.x*a2.x + a2.y*a2.y + a2.z*a2.z + a2.w*a2.w
                 + a3.x*a3.x + a3.y*a3.y + a3.z*a3.z + a3.w*a3.w;
        float s1 = b0.x*b0.x + b0.y*b0.y + b0.z*b0.z + b0.w*b0.w
                 + b1.x*b1.x + b1.y*b1.y + b1.z*b1.z + b1.w*b1.w
                 + b2.x*b2.x + b2.y*b2.y + b2.z*b2.z + b2.w*b2.w
                 + b3.x*b3.x + b3.y*b3.y + b3.z*b3.z + b3.w*b3.w;

        float d0 = fmaxf(ATT_NORM * (sqrtf(s0) + __uint_as_float(m.x)), EPS_V);
        float d1 = fmaxf(ATT_NORM * (sqrtf(s1) + __uint_as_float(m.y)), EPS_V);

        v2f o;
        o.x = fminf(fmaxf(ev.x, -10000.0f), 10000.0f) / d0;
        o.y = fminf(fmaxf(ev.y, -10000.0f), 10000.0f) / d1;
        *(v2f*)(out + (size_t)e * NHEADS + hp * 2) = o;
    }
}

extern "C" void kernel_launch(void* const* d_in, const int* in_sizes, int n_in,
                              void* d_out, int out_size, void* d_ws, size_t ws_size,
                              hipStream_t stream) {
    const float* e_ij  = (const float*)d_in[0];
    const float* x_i   = (const float*)d_in[1];
    const float* x_j   = (const float*)d_in[2];
    const int*   index = (const int*)d_in[3];

    float* out = (float*)d_out;
    unsigned int* node_max = (unsigned int*)d_ws;   // [NNODES][NHEADS]

    const int EH  = out_size;        // E * NHEADS = 12.8M
    const int EH2 = EH / 2;          // E * 4 head-pairs
    const int threads = 256;
    const int maxBlocks = 2048;      // G11: cap + grid-stride for memory-bound

    int blocks1 = (EH + threads - 1) / threads;
    if (blocks1 > maxBlocks) blocks1 = maxBlocks;
    int blocks2 = (EH2 + threads - 1) / threads;
    if (blocks2 > maxBlocks) blocks2 = maxBlocks;

    // Zero the segment-max scratch every call (harness does not re-poison).
    (void)hipMemsetAsync(node_max, 0, (size_t)NNODES * NHEADS * sizeof(unsigned int), stream);

    lips_pass1<<<blocks1, threads, 0, stream>>>(x_j, index, node_max, EH);
    lips_pass2<<<blocks2, threads, 0, stream>>>(e_ij, x_i, index, node_max, out, EH2);
}

// Round 5
// 343.352 us; speedup vs baseline: 1.4458x; 1.0342x over previous
//
#include <hip/hip_runtime.h>

#define NNODES   50000
#define NHEADS   8
#define NCHAN    16
#define ATT_NORM 4.0f
#define EPS_V    1e-12f

typedef float v4f __attribute__((ext_vector_type(4)));

// Pass 1: per-(edge,head) L2 norm of x_j, segment-max into node_max via
// unsigned atomicMax (norms >= 0: IEEE754 order == uint order).
// Read-check-skip with a PLAIN load (L1/L2-cacheable; R3's agent-scope
// atomic-load forced fabric reads and regressed). Safe because node_max
// is monotone non-decreasing from 0: any stale cached value is <= current,
// so skipping when stale >= nj is correct; redundant atomics are harmless.
__global__ void lips_pass1(const float* __restrict__ x_j,
                           const int* __restrict__ index,
                           unsigned int* node_max,
                           int EH) {
    int t = blockIdx.x * blockDim.x + threadIdx.x;
    if (t >= EH) return;
    const int e = t >> 3;   // / NHEADS
    const int h = t & 7;    // % NHEADS

    const v4f* p = (const v4f*)(x_j + (size_t)t * NCHAN);
    v4f a = p[0], b = p[1], c = p[2], d = p[3];
    float s = a.x*a.x + a.y*a.y + a.z*a.z + a.w*a.w
            + b.x*b.x + b.y*b.y + b.z*b.z + b.w*b.w
            + c.x*c.x + c.y*c.y + c.z*c.z + c.w*c.w
            + d.x*d.x + d.y*d.y + d.z*d.z + d.w*d.w;
    unsigned int nj = __float_as_uint(sqrtf(s));

    const int node = index[e];
    unsigned int* slot = node_max + (size_t)node * NHEADS + h;
    if (*slot < nj) {
        atomicMax(slot, nj);
    }
}

// Pass 2: recompute ni from x_i (lane-contiguous 64 B/thread), gather node
// max, divide. One (edge,head) per thread — R4 showed 128 B/thread strided
// loads quadruple transaction pressure and regress.
__global__ void lips_pass2(const float* __restrict__ e_ij,
                           const float* __restrict__ x_i,
                           const int* __restrict__ index,
                           const unsigned int* __restrict__ node_max,
                           float* __restrict__ out,
                           int EH) {
    int t = blockIdx.x * blockDim.x + threadIdx.x;
    if (t >= EH) return;
    const int e = t >> 3;
    const int h = t & 7;

    const v4f* p = (const v4f*)(x_i + (size_t)t * NCHAN);
    v4f a = p[0], b = p[1], c = p[2], d = p[3];
    float s = a.x*a.x + a.y*a.y + a.z*a.z + a.w*a.w
            + b.x*b.x + b.y*b.y + b.z*b.z + b.w*b.w
            + c.x*c.x + c.y*c.y + c.z*c.z + c.w*c.w
            + d.x*d.x + d.y*d.y + d.z*d.z + d.w*d.w;
    float ni = sqrtf(s);

    const int node = index[e];
    float mnj = __uint_as_float(node_max[(size_t)node * NHEADS + h]);

    float denom = ATT_NORM * (ni + mnj);
    denom = fmaxf(denom, EPS_V);

    float ev = e_ij[t];
    ev = fminf(fmaxf(ev, -10000.0f), 10000.0f);
    out[t] = ev / denom;
}

extern "C" void kernel_launch(void* const* d_in, const int* in_sizes, int n_in,
                              void* d_out, int out_size, void* d_ws, size_t ws_size,
                              hipStream_t stream) {
    const float* e_ij  = (const float*)d_in[0];
    const float* x_i   = (const float*)d_in[1];
    const float* x_j   = (const float*)d_in[2];
    const int*   index = (const int*)d_in[3];

    float* out = (float*)d_out;
    unsigned int* node_max = (unsigned int*)d_ws;   // [NNODES][NHEADS]

    const int EH = out_size;                        // E * NHEADS = 12.8M
    const int threads = 256;
    const int blocks = (EH + threads - 1) / threads;

    // Zero the segment-max scratch every call (harness does not re-poison).
    (void)hipMemsetAsync(node_max, 0, (size_t)NNODES * NHEADS * sizeof(unsigned int), stream);

    lips_pass1<<<blocks, threads, 0, stream>>>(x_j, index, node_max, EH);
    lips_pass2<<<blocks, threads, 0, stream>>>(e_ij, x_i, index, node_max, out, EH);
}

// Round 6
// 334.602 us; speedup vs baseline: 1.4836x; 1.0261x over previous
//
#include <hip/hip_runtime.h>

#define NNODES   50000
#define NHEADS   8
#define NCHAN    16
#define ATT_NORM 4.0f
#define EPS_V    1e-12f

typedef float v4f __attribute__((ext_vector_type(4)));

// Pass 1: per-(edge,head) L2 norm of x_j, segment-max via unsigned atomicMax
// (norms >= 0: IEEE754 order == uint order). Two elements per thread,
// vertically split (t, t+half): each half-stream stays perfectly
// lane-contiguous (R1 layout), but ILP doubles to 8 in-flight dwordx4.
__global__ void lips_pass1(const float* __restrict__ x_j,
                           const int* __restrict__ index,
                           unsigned int* __restrict__ node_max,
                           int half) {
    int t0 = blockIdx.x * blockDim.x + threadIdx.x;
    if (t0 >= half) return;
    int t1 = t0 + half;

    const int e0 = t0 >> 3, h0 = t0 & 7;
    const int e1 = t1 >> 3, h1 = t1 & 7;
    const int node0 = index[e0];
    const int node1 = index[e1];

    const v4f* p0 = (const v4f*)(x_j + (size_t)t0 * NCHAN);
    const v4f* p1 = (const v4f*)(x_j + (size_t)t1 * NCHAN);
    v4f a0 = p0[0], b0 = p0[1], c0 = p0[2], d0 = p0[3];
    v4f a1 = p1[0], b1 = p1[1], c1 = p1[2], d1 = p1[3];

    float s0 = a0.x*a0.x + a0.y*a0.y + a0.z*a0.z + a0.w*a0.w
             + b0.x*b0.x + b0.y*b0.y + b0.z*b0.z + b0.w*b0.w
             + c0.x*c0.x + c0.y*c0.y + c0.z*c0.z + c0.w*c0.w
             + d0.x*d0.x + d0.y*d0.y + d0.z*d0.z + d0.w*d0.w;
    float s1 = a1.x*a1.x + a1.y*a1.y + a1.z*a1.z + a1.w*a1.w
             + b1.x*b1.x + b1.y*b1.y + b1.z*b1.z + b1.w*b1.w
             + c1.x*c1.x + c1.y*c1.y + c1.z*c1.z + c1.w*c1.w
             + d1.x*d1.x + d1.y*d1.y + d1.z*d1.z + d1.w*d1.w;

    atomicMax(node_max + (size_t)node0 * NHEADS + h0, __float_as_uint(sqrtf(s0)));
    atomicMax(node_max + (size_t)node1 * NHEADS + h1, __float_as_uint(sqrtf(s1)));
}

// Pass 2: recompute ni from x_i, gather node max, divide. Same two-element
// vertical split for ILP; per-half layout identical to R1.
__global__ void lips_pass2(const float* __restrict__ e_ij,
                           const float* __restrict__ x_i,
                           const int* __restrict__ index,
                           const unsigned int* __restrict__ node_max,
                           float* __restrict__ out,
                           int half) {
    int t0 = blockIdx.x * blockDim.x + threadIdx.x;
    if (t0 >= half) return;
    int t1 = t0 + half;

    const int e0 = t0 >> 3, h0 = t0 & 7;
    const int e1 = t1 >> 3, h1 = t1 & 7;
    const int node0 = index[e0];
    const int node1 = index[e1];

    const v4f* p0 = (const v4f*)(x_i + (size_t)t0 * NCHAN);
    const v4f* p1 = (const v4f*)(x_i + (size_t)t1 * NCHAN);
    v4f a0 = p0[0], b0 = p0[1], c0 = p0[2], d0 = p0[3];
    v4f a1 = p1[0], b1 = p1[1], c1 = p1[2], d1 = p1[3];

    float ev0 = e_ij[t0];
    float ev1 = e_ij[t1];
    float m0 = __uint_as_float(node_max[(size_t)node0 * NHEADS + h0]);
    float m1 = __uint_as_float(node_max[(size_t)node1 * NHEADS + h1]);

    float s0 = a0.x*a0.x + a0.y*a0.y + a0.z*a0.z + a0.w*a0.w
             + b0.x*b0.x + b0.y*b0.y + b0.z*b0.z + b0.w*b0.w
             + c0.x*c0.x + c0.y*c0.y + c0.z*c0.z + c0.w*c0.w
             + d0.x*d0.x + d0.y*d0.y + d0.z*d0.z + d0.w*d0.w;
    float s1 = a1.x*a1.x + a1.y*a1.y + a1.z*a1.z + a1.w*a1.w
             + b1.x*b1.x + b1.y*b1.y + b1.z*b1.z + b1.w*b1.w
             + c1.x*c1.x + c1.y*c1.y + c1.z*c1.z + c1.w*c1.w
             + d1.x*d1.x + d1.y*d1.y + d1.z*d1.z + d1.w*d1.w;

    float den0 = fmaxf(ATT_NORM * (sqrtf(s0) + m0), EPS_V);
    float den1 = fmaxf(ATT_NORM * (sqrtf(s1) + m1), EPS_V);

    out[t0] = fminf(fmaxf(ev0, -10000.0f), 10000.0f) / den0;
    out[t1] = fminf(fmaxf(ev1, -10000.0f), 10000.0f) / den1;
}

extern "C" void kernel_launch(void* const* d_in, const int* in_sizes, int n_in,
                              void* d_out, int out_size, void* d_ws, size_t ws_size,
                              hipStream_t stream) {
    const float* e_ij  = (const float*)d_in[0];
    const float* x_i   = (const float*)d_in[1];
    const float* x_j   = (const float*)d_in[2];
    const int*   index = (const int*)d_in[3];

    float* out = (float*)d_out;
    unsigned int* node_max = (unsigned int*)d_ws;   // [NNODES][NHEADS]

    const int EH   = out_size;       // E * NHEADS = 12.8M (even)
    const int half = EH / 2;
    const int threads = 256;
    const int blocks = (half + threads - 1) / threads;

    // Zero the segment-max scratch every call (harness does not re-poison;
    // 0xAA poison is a huge uint and would win every atomicMax).
    (void)hipMemsetAsync(node_max, 0, (size_t)NNODES * NHEADS * sizeof(unsigned int), stream);

    lips_pass1<<<blocks, threads, 0, stream>>>(x_j, index, node_max, half);
    lips_pass2<<<blocks, threads, 0, stream>>>(e_ij, x_i, index, node_max, out, half);
}

// Round 7
// 313.883 us; speedup vs baseline: 1.5816x; 1.0660x over previous
//
#include <hip/hip_runtime.h>

#define NNODES   50000
#define NHEADS   8
#define NCHAN    16
#define ATT_NORM 4.0f
#define EPS_V    1e-12f

// Best measured variant (R1, 313.8 us = 5.59 TB/s effective on 1.754 GB
// minimal traffic, 89% of pure-copy ceiling). Four structural perturbations
// (NT loads + agent-scope pre-check, 2-head/thread, plain-load pre-check,
// ILP-2 vertical split) all regressed — this layout is locally optimal.

// Pass 1: per-(edge,head) L2 norm of x_j, segment-max into node_max via
// unsigned atomicMax (valid because norms are >= 0: IEEE754 order == uint order).
__global__ void lips_pass1(const float* __restrict__ x_j,
                           const int* __restrict__ index,
                           unsigned int* __restrict__ node_max,
                           int EH) {
    int t = blockIdx.x * blockDim.x + threadIdx.x;
    if (t >= EH) return;
    const int e = t >> 3;   // / NHEADS
    const int h = t & 7;    // % NHEADS

    const float4* p = (const float4*)(x_j + (size_t)t * NCHAN);
    float4 a = p[0], b = p[1], c = p[2], d = p[3];
    float s = a.x*a.x + a.y*a.y + a.z*a.z + a.w*a.w
            + b.x*b.x + b.y*b.y + b.z*b.z + b.w*b.w
            + c.x*c.x + c.y*c.y + c.z*c.z + c.w*c.w
            + d.x*d.x + d.y*d.y + d.z*d.z + d.w*d.w;
    float nj = sqrtf(s);

    int node = index[e];
    atomicMax(node_max + (size_t)node * NHEADS + h, __float_as_uint(nj));
}

// Pass 2: recompute ni from x_i (lane-contiguous 64 B/thread), gather node
// max, divide.
__global__ void lips_pass2(const float* __restrict__ e_ij,
                           const float* __restrict__ x_i,
                           const int* __restrict__ index,
                           const unsigned int* __restrict__ node_max,
                           float* __restrict__ out,
                           int EH) {
    int t = blockIdx.x * blockDim.x + threadIdx.x;
    if (t >= EH) return;
    const int e = t >> 3;
    const int h = t & 7;

    const float4* p = (const float4*)(x_i + (size_t)t * NCHAN);
    float4 a = p[0], b = p[1], c = p[2], d = p[3];
    float s = a.x*a.x + a.y*a.y + a.z*a.z + a.w*a.w
            + b.x*b.x + b.y*b.y + b.z*b.z + b.w*b.w
            + c.x*c.x + c.y*c.y + c.z*c.z + c.w*c.w
            + d.x*d.x + d.y*d.y + d.z*d.z + d.w*d.w;
    float ni = sqrtf(s);

    int node = index[e];
    float mnj = __uint_as_float(node_max[(size_t)node * NHEADS + h]);

    float denom = ATT_NORM * (ni + mnj);
    denom = fmaxf(denom, EPS_V);

    float ev = e_ij[t];
    ev = fminf(fmaxf(ev, -10000.0f), 10000.0f);
    out[t] = ev / denom;
}

extern "C" void kernel_launch(void* const* d_in, const int* in_sizes, int n_in,
                              void* d_out, int out_size, void* d_ws, size_t ws_size,
                              hipStream_t stream) {
    const float* e_ij  = (const float*)d_in[0];
    const float* x_i   = (const float*)d_in[1];
    const float* x_j   = (const float*)d_in[2];
    const int*   index = (const int*)d_in[3];

    float* out = (float*)d_out;
    unsigned int* node_max = (unsigned int*)d_ws;   // [NNODES][NHEADS]

    const int EH = out_size;                        // E * NHEADS = 12.8M
    const int threads = 256;
    const int blocks = (EH + threads - 1) / threads;

    // Zero the segment-max scratch every call (harness does not re-poison;
    // 0xAA poison is a huge uint and would win every atomicMax).
    (void)hipMemsetAsync(node_max, 0, (size_t)NNODES * NHEADS * sizeof(unsigned int), stream);

    lips_pass1<<<blocks, threads, 0, stream>>>(x_j, index, node_max, EH);
    lips_pass2<<<blocks, threads, 0, stream>>>(e_ij, x_i, index, node_max, out, EH);
}